// Round 1
// 78.957 us; speedup vs baseline: 1.0216x; 1.0216x over previous
//
#include <hip/hip_runtime.h>
#include <stdint.h>
#include <math.h>

#define NB 8
#define NQ 512

typedef unsigned long long u64;

// Word-major (transposed) cost tile: word k (columns 64k..64k+63) of row r.
// Row-major [row][8] had bank = (16*lane + 2k) % 32 in the 4-wave scans ->
// all 64 lanes on 2 bank-pairs = ~32-way conflict (~16 B/cyc effective).
// Word-major gives bank = 2*lane % 32 -> minimal aliasing (conflict-free).
#define CW(k, r) costL[((k) << 9) + (r)]

// ---- register-array helpers: constant-index-only access (no scratch spills) ----
static __device__ __forceinline__ u64 getw8(const u64 (&a)[8], int w) {
    u64 r = 0ull;
#pragma unroll
    for (int k = 0; k < 8; k++) if (k == w) r = a[k];
    return r;
}
static __device__ __forceinline__ void setbit8(u64 (&a)[8], int c) {
    int w = c >> 6; u64 m = 1ull << (c & 63);
#pragma unroll
    for (int k = 0; k < 8; k++) if (k == w) a[k] |= m;
}
static __device__ __forceinline__ bool getbit8(const u64 (&a)[8], int c) {
    return (getw8(a, c >> 6) >> (c & 63)) & 1ull;
}

// Fused prep+cost: xyxy conversions inline (bit-identical to reference:
// Kalman innovation == 0 exactly, so filtered = (prev*scale)/scale).
// Writes the cost bitmatrix TRANSPOSED (word-major): cost[b*4096 + (j>>6)*512 + i]
__global__ void cost_kernel(const float* __restrict__ prev_boxes,
                            const float* __restrict__ curr_boxes,
                            const float* __restrict__ image_sizes,
                            u64* __restrict__ cost,
                            float* __restrict__ out) {
#pragma clang fp contract(off)
    int t = blockIdx.x * blockDim.x + threadIdx.x;   // 0 .. NB*NQ*NQ-1
    if (t == 0) out[0] = 0.f;
    int b = t >> 18;
    int rem = t & (NQ * NQ - 1);
    int i = rem >> 9;        // row: curr box
    int j = rem & (NQ - 1);  // col: filtered box
    float4 cb = ((const float4*)curr_boxes)[(b << 9) + i];
    float ax = cb.x - 0.5f * cb.z, ay = cb.y - 0.5f * cb.w;
    float az = cb.x + 0.5f * cb.z, aw = cb.y + 0.5f * cb.w;
    float H = image_sizes[2 * b + 0];
    float W = image_sizes[2 * b + 1];
    float4 pb = ((const float4*)prev_boxes)[(b << 9) + j];
    float fcx = (pb.x * W) / W, fcy = (pb.y * H) / H;
    float fw  = (pb.z * W) / W, fh  = (pb.w * H) / H;
    float bx = fcx - 0.5f * fw, by = fcy - 0.5f * fh;
    float bz = fcx + 0.5f * fw, bw = fcy + 0.5f * fh;
    float area_a = (az - ax) * (aw - ay);
    float area_b = (bz - bx) * (bw - by);
    float ltx = fmaxf(ax, bx), lty = fmaxf(ay, by);
    float rbx = fminf(az, bz), rby = fminf(aw, bw);
    float w = fmaxf(rbx - ltx, 0.f), h = fmaxf(rby - lty, 0.f);
    float inter = w * h;
    float uni = area_a + area_b - inter;
    float iou = inter / (uni + 1e-7f);
    float lcx = fminf(ax, bx), lcy = fminf(ay, by);
    float rcx = fmaxf(az, bz), rcy = fmaxf(aw, bw);
    float wc = fmaxf(rcx - lcx, 0.f), hc = fmaxf(rcy - lcy, 0.f);
    float areac = wc * hc;
    float giou = iou - (areac - uni) / (areac + 1e-7f);
    float gl = 1.f - giou;
    u64 m = __ballot(gl < 0.2f);
    if ((threadIdx.x & 63) == 0)
        cost[(size_t)b * (NQ * 8) + ((size_t)(j >> 6) << 9) + i] = m;
}

// Exact integer replication of the reference JV Hungarian on a {0,1} cost
// matrix + fused CIoU epilogue. R10: word-major (transposed) LDS cost tile
// removes the ~32-way bank conflict in the 4-wave ballot/apB scans (the
// dominant cost at R9's 80 µs); recompute also skips word-groups below the
// current cursor word (rows already retired are never re-read via intW).
__global__ __launch_bounds__(256, 1) void hungarian_kernel(
        const u64* __restrict__ cost,
        const float* __restrict__ prev_boxes,
        const float* __restrict__ curr_boxes,
        const float* __restrict__ image_sizes,
        float* __restrict__ out) {
    int b = blockIdx.x;
    int tid = threadIdx.x;
    int lane = tid & 63;
    int wv = tid >> 6;
    __shared__ __align__(16) u64 costL[NQ * 8];   // 32 KB, word-major
    __shared__ int p[NQ + 1];
    __shared__ int wayL[NQ + 1];
    __shared__ int u[NQ + 1];
    __shared__ int vv[NQ + 1];
    __shared__ int minvA[NQ + 1];
    __shared__ unsigned char used[NQ + 1];
    __shared__ u64 nzS[8], c0S[8], dgS[8], apS[8], zcS[8];
    __shared__ int actionS;
    __shared__ int wIdxS;

    {
        // global buffer is already word-major per batch -> straight copy
        const ulonglong2* src = (const ulonglong2*)(cost + (size_t)b * NQ * 8);
        ulonglong2* dst = (ulonglong2*)costL;
        for (int k = tid; k < NQ * 4; k += 256) dst[k] = src[k];
    }
    for (int k = tid; k <= NQ; k += 256) { p[k] = k; wayL[k] = 0; u[k] = 0; vv[k] = 0; }
    __syncthreads();

    // 4-wave ballot precompute: wave wv owns word-groups 2wv, 2wv+1
#pragma unroll
    for (int gi = 0; gi < 2; gi++) {
        int g = 2 * wv + gi;
        int r = (g << 6) + lane;
        u64 o = 0ull, w0 = 0ull, wg = 0ull;
#pragma unroll
        for (int k = 0; k < 8; k++) {
            u64 x = CW(k, r);
            o |= x;
            if (k == 0) w0 = x;
            if (k == g) wg = x;
        }
        u64 nzb = __ballot(o != 0ull);
        u64 c0b = __ballot((w0 & 1ull) != 0ull);
        u64 dgb = __ballot(((wg >> lane) & 1ull) != 0ull);
        if (lane == 0) { nzS[g] = nzb; c0S[g] = c0b; dgS[g] = dgb; apS[g] = 0ull; }
    }
    __syncthreads();

    // thread-0 serial state (persists across block-loop iterations)
    u64 nzB[8], c0B[8], dgB[8], apB[8];
    bool ownerNZ0 = false;
    int owner0 = 1;
    u64 Zc[8];
    int wIdx = 0;
    u64 bits = 0ull, pendMask = ~0ull;
    bool started = false;
    if (tid == 0) {
#pragma unroll
        for (int k = 0; k < 8; k++) { nzB[k] = nzS[k]; c0B[k] = c0S[k]; dgB[k] = dgS[k]; apB[k] = 0ull; Zc[k] = 0ull; }
    }

    auto intW = [&](int w) -> u64 {
        u64 x = getw8(c0B, w) | getw8(dgB, w);
        if (ownerNZ0) x |= getw8(apB, w);
        return getw8(nzB, w) & x;
    };
    auto runGeneral = [&](int igen) {
        // exact general integer JV for rows igen..NQ (reference semantics).
        // occupied cols are contiguous 1..igen-1; zero p for free cols so
        // the p[j0]==0 free test works (identity was prewritten).
        for (int j = igen; j <= NQ; j++) p[j] = 0;
        for (int i2 = igen; i2 <= NQ; i2++) {
            p[0] = i2;
            for (int j = 0; j <= NQ; j++) { minvA[j] = 0x7fffffff; used[j] = 0; }
            int j0 = 0;
            while (true) {
                used[j0] = 1;
                int i0 = p[j0];
                int ui0 = u[i0];
                int delta = 0x7fffffff, j1 = 0;
                for (int j = 1; j <= NQ; j++) {
                    if (!used[j]) {
                        int cbit = (int)((CW((j - 1) >> 6, i0 - 1) >> ((j - 1) & 63)) & 1ull);
                        int cur = cbit - ui0 - vv[j];
                        if (cur < minvA[j]) { minvA[j] = cur; wayL[j] = (i2 << 10) | j0; }
                        if (minvA[j] < delta) { delta = minvA[j]; j1 = j; }
                    }
                }
                for (int j = 0; j <= NQ; j++) {
                    if (used[j]) { u[p[j]] += delta; vv[j] -= delta; }
                    else minvA[j] -= delta;
                }
                j0 = j1;
                if (p[j0] == 0) break;
            }
            while (j0) {
                int wv2 = wayL[j0];
                int jn = ((wv2 >> 10) == i2) ? (wv2 & 1023) : 0;
                p[j0] = p[jn];
                j0 = jn;
            }
        }
    };

    for (;;) {   // block-uniform loop
        if (tid == 0) {
            int action = 0;   // 1 = recompute apB (Zc changed), 3 = done
            if (!started) {
                started = true;
                if (nzB[0] & 1ull) {
                    // row 1 special: col0 is free (cursor=0)
                    u64 Z1[8];
#pragma unroll
                    for (int k = 0; k < 8; k++) Z1[k] = CW(k, 0);
                    if (!(Z1[0] & 1ull)) {
                        owner0 = 1; ownerNZ0 = true;
#pragma unroll
                        for (int k = 0; k < 8; k++) Zc[k] = Z1[k];
                        action = 1; pendMask = ~1ull; wIdx = 0;
                    } else {
                        runGeneral(1); action = 3;
                    }
                } else {
                    bits = intW(0) & ~1ull;
                }
            }
            while (action == 0) {
                if (bits == 0ull) {
                    wIdx++;
                    if (wIdx >= 8) { action = 3; break; }
                    bits = intW(wIdx);
                    continue;
                }
                int l = __builtin_ctzll(bits);
                bits &= bits - 1;
                u64 rem = (l == 63) ? 0ull : (~0ull << (l + 1));
                int i = (wIdx << 6) + l + 1;   // 1-based row; cursor col = i-1
                bool c0 = (getw8(c0B, wIdx) >> l) & 1ull;
                bool apb = ownerNZ0 && ((getw8(apB, wIdx) >> l) & 1ull);
                if (!c0 && !apb) {
                    // diag event: relocation (zero owner0) / swap (nz owner0,
                    // ap==0 guarantees Zc[i-1]==0). p[i]=owner0, p[1]=i.
                    p[i] = owner0;
                    p[1] = i;
                    owner0 = i; ownerNZ0 = true;
#pragma unroll
                    for (int k = 0; k < 8; k++) Zc[k] = CW(k, i - 1);
                    action = 1; pendMask = rem;
                } else {
                    // full bitset search (zero duals)
                    int prevO = owner0; bool prevF = ownerNZ0;
                    bool bail = false, hole = false;
                    u64 Z[8];
#pragma unroll
                    for (int k = 0; k < 8; k++) Z[k] = CW(k, i - 1);
                    u64 ones[8], vis[8], nzA[8], nzBf[8];
#pragma unroll
                    for (int k = 0; k < 8; k++) { ones[k] = Z[k]; vis[k] = 0ull; nzA[k] = 0ull; nzBf[k] = 0ull; }
                    int fA_c = 0, fA_p = 0, fB_c = 0, fB_p = 0;
                    int foldn = 0, assignTo = -1;
                    while (true) {
                        int c2 = -1;
#pragma unroll
                        for (int k = 7; k >= 0; k--) {
                            u64 s = ~ones[k] & ~vis[k];
                            if (s != 0ull) c2 = (k << 6) + __builtin_ctzll(s);
                        }
                        if (c2 < 0) { bail = true; break; }       // delta>0 needed
                        if (c2 >= i - 1) {                        // free region
                            if (c2 == i - 1) assignTo = c2;
                            else hole = true;                     // free above cursor
                            break;
                        }
                        int pc = p[c2 + 1];
                        u64 Zo[8];
#pragma unroll
                        for (int k = 0; k < 8; k++) Zo[k] = CW(k, pc - 1);
                        setbit8(vis, c2);
                        u64 nzv[8], ap2 = 0ull;
#pragma unroll
                        for (int k = 0; k < 8; k++) { nzv[k] = ones[k] & ~Zo[k]; ones[k] &= Zo[k]; ap2 |= ones[k]; }
                        if (foldn == 0) {
                            fA_c = c2; fA_p = pc;
#pragma unroll
                            for (int k = 0; k < 8; k++) nzA[k] = nzv[k];
                        } else if (foldn == 1) {
                            fB_c = c2; fB_p = pc;
#pragma unroll
                            for (int k = 0; k < 8; k++) nzBf[k] = nzv[k];
                        } else {
#pragma unroll
                            for (int k = 0; k < 8; k++) {
                                u64 tt = nzv[k];
                                while (tt) { int b2 = __builtin_ctzll(tt); tt &= tt - 1; wayL[(k << 6) + b2 + 1] = (i << 10) | (c2 + 1); }
                            }
                        }
                        foldn++;
                        if (ap2 == 0ull) { assignTo = i - 1; break; }   // shortcut -> cursor
                    }
                    if (bail || hole) {
                        runGeneral(i);
                        action = 3;
                    } else {
                        int cc = assignTo;
                        while (true) {
                            bool inA = getbit8(nzA, cc), inB = getbit8(nzBf, cc);
                            if (inB)      { p[cc + 1] = fB_p; cc = fB_c; }
                            else if (inA) { p[cc + 1] = fA_p; cc = fA_c; }
                            else if (foldn > 2) {
                                int wv2 = wayL[cc + 1];
                                if ((wv2 >> 10) == i) { int jn = wv2 & 1023; p[cc + 1] = p[jn]; cc = jn - 1; }
                                else                  { p[cc + 1] = i; break; }
                            } else { p[cc + 1] = i; break; }
                        }
                        owner0 = p[1];
                        ownerNZ0 = (getw8(nzB, (owner0 - 1) >> 6) >> ((owner0 - 1) & 63)) & 1ull;
                        if (ownerNZ0 && !(prevF && prevO == owner0)) {
#pragma unroll
                            for (int k = 0; k < 8; k++) Zc[k] = CW(k, owner0 - 1);
                            action = 1; pendMask = rem;
                        } else {
                            bits = intW(wIdx) & rem;
                        }
                    }
                }
            }
            if (action == 1) {
#pragma unroll
                for (int k = 0; k < 8; k++) zcS[k] = Zc[k];
                wIdxS = wIdx;
            }
            actionS = action;
        }
        __syncthreads();
        int action = actionS;
        if (action == 1) {
            // 4-wave recompute of apB: wave wv owns word-groups 2wv, 2wv+1.
            // Word-major tile -> lane-consecutive rows -> conflict-free.
            // Groups below the cursor word are never re-read via intW: skip.
            u64 zc[8];
#pragma unroll
            for (int k = 0; k < 8; k++) zc[k] = zcS[k];
            int w0 = wIdxS;
#pragma unroll
            for (int gi = 0; gi < 2; gi++) {
                int g = 2 * wv + gi;
                if (g >= w0) {
                    int r = (g << 6) + lane;
                    u64 a = 0ull;
#pragma unroll
                    for (int k = 0; k < 8; k++) a |= CW(k, r) & zc[k];
                    u64 bal = __ballot(a != 0ull);
                    if (lane == 0) apS[g] = bal;
                }
            }
            __syncthreads();
            if (tid == 0) {
#pragma unroll
                for (int k = 0; k < 8; k++) apB[k] = apS[k];
                ownerNZ0 = true;
                bits = intW(wIdx) & pendMask;
            }
            continue;
        }
        break;   // action == 3
    }
    __syncthreads();

    // Fused CIoU epilogue: p is a permutation, so summing over columns j
    // (curr idx j-1, filtered idx p[j]-1) == summing over rows.
    {
#pragma clang fp contract(off)
        float H = image_sizes[2 * b + 0];
        float W = image_sizes[2 * b + 1];
        float sum = 0.f;
#pragma unroll
        for (int k = 0; k < 2; k++) {
            int j = 1 + tid + (k << 8);
            int r = p[j] - 1;     // filtered row
            int c = j - 1;        // curr box index
            float4 cb = ((const float4*)curr_boxes)[(b << 9) + c];
            float x1 = cb.x - 0.5f * cb.z, y1 = cb.y - 0.5f * cb.w;
            float x2 = cb.x + 0.5f * cb.z, y2 = cb.y + 0.5f * cb.w;
            float4 pb = ((const float4*)prev_boxes)[(b << 9) + r];
            float fcx = (pb.x * W) / W, fcy = (pb.y * H) / H;
            float fw2 = (pb.z * W) / W, fh2 = (pb.w * H) / H;
            float xg1 = fcx - 0.5f * fw2, yg1 = fcy - 0.5f * fh2;
            float xg2 = fcx + 0.5f * fw2, yg2 = fcy + 0.5f * fh2;
            float iw = fmaxf(fminf(x2, xg2) - fmaxf(x1, xg1), 0.f);
            float ih = fmaxf(fminf(y2, yg2) - fmaxf(y1, yg1), 0.f);
            float inter = iw * ih;
            float uni = (x2 - x1) * (y2 - y1) + (xg2 - xg1) * (yg2 - yg1) - inter;
            float iou = inter / (uni + 1e-7f);
            float cw2 = fmaxf(x2, xg2) - fminf(x1, xg1);
            float ch2 = fmaxf(y2, yg2) - fminf(y1, yg1);
            float c2 = cw2 * cw2 + ch2 * ch2 + 1e-7f;
            float dx = ((x1 + x2) - xg1) - xg2;
            float dy = ((y1 + y2) - yg1) - yg2;
            float d2 = (dx * dx + dy * dy) / 4.f;
            const float CC = (float)(4.0 / (M_PI * M_PI));
            float at = atanf((xg2 - xg1) / (yg2 - yg1)) - atanf((x2 - x1) / (y2 - y1));
            float v = CC * (at * at);
            float alpha = v / (((1.f - iou) + v) + 1e-7f);
            sum += ((1.f - iou) + d2 / c2) + alpha * v;
        }
#pragma unroll
        for (int off = 32; off >= 1; off >>= 1) sum += __shfl_xor(sum, off, 64);
        if (lane == 0) atomicAdd(out, sum * (1.f / 4096.f));
    }
}

extern "C" void kernel_launch(void* const* d_in, const int* in_sizes, int n_in,
                              void* d_out, int out_size, void* d_ws, size_t ws_size,
                              hipStream_t stream) {
    const float* prev_boxes  = (const float*)d_in[0];
    // d_in[1] = prev_logits : dead code (Kalman innovation == 0 exactly)
    const float* curr_boxes  = (const float*)d_in[2];
    const float* image_sizes = (const float*)d_in[3];
    // d_in[4..6] (std weights, log_q_diag) : dead code

    u64* cost = (u64*)d_ws;
    float* out = (float*)d_out;

    cost_kernel<<<(NB * NQ * NQ) / 256, 256, 0, stream>>>(
        prev_boxes, curr_boxes, image_sizes, cost, out);
    hungarian_kernel<<<NB, 256, 0, stream>>>(
        cost, prev_boxes, curr_boxes, image_sizes, out);
}

// Round 2
// 77.722 us; speedup vs baseline: 1.0378x; 1.0159x over previous
//
#include <hip/hip_runtime.h>
#include <stdint.h>
#include <math.h>

#define NB 8
#define NQ 512

typedef unsigned long long u64;

// Word-major (transposed) cost tile: word k (columns 64k..64k+63) of row r.
#define CW(k, r) costL[((k) << 9) + (r)]

// ---- register-array helpers: constant-index-only access (no scratch spills) ----
static __device__ __forceinline__ u64 getw8(const u64 (&a)[8], int w) {
    u64 r = 0ull;
#pragma unroll
    for (int k = 0; k < 8; k++) if (k == w) r = a[k];
    return r;
}
static __device__ __forceinline__ void setbit8(u64 (&a)[8], int c) {
    int w = c >> 6; u64 m = 1ull << (c & 63);
#pragma unroll
    for (int k = 0; k < 8; k++) if (k == w) a[k] |= m;
}
static __device__ __forceinline__ bool getbit8(const u64 (&a)[8], int c) {
    return (getw8(a, c >> 6) >> (c & 63)) & 1ull;
}

// R11a: hoist the filtered-box conversion (4 IEEE divides) out of the
// 2M-thread cost kernel: computed once per (b,j) instead of 512x.
// Ops bit-identical to the previous inline sequence (fp contract off).
__global__ void prep_kernel(const float* __restrict__ prev_boxes,
                            const float* __restrict__ image_sizes,
                            float4* __restrict__ filt,
                            float* __restrict__ out) {
#pragma clang fp contract(off)
    int t = blockIdx.x * blockDim.x + threadIdx.x;   // 0 .. NB*NQ-1
    if (t == 0) out[0] = 0.f;
    int b = t >> 9;
    float4 pb = ((const float4*)prev_boxes)[t];
    float H = image_sizes[2 * b + 0];
    float W = image_sizes[2 * b + 1];
    float fcx = (pb.x * W) / W, fcy = (pb.y * H) / H;
    float fw  = (pb.z * W) / W, fh  = (pb.w * H) / H;
    filt[t] = make_float4(fcx - 0.5f * fw, fcy - 0.5f * fh,
                          fcx + 0.5f * fw, fcy + 0.5f * fh);
}

// Fused cost: reads prepped filtered xyxy; writes the cost bitmatrix
// TRANSPOSED (word-major): cost[b*4096 + (j>>6)*512 + i]
__global__ void cost_kernel(const float* __restrict__ curr_boxes,
                            const float4* __restrict__ filt,
                            u64* __restrict__ cost) {
#pragma clang fp contract(off)
    int t = blockIdx.x * blockDim.x + threadIdx.x;   // 0 .. NB*NQ*NQ-1
    int b = t >> 18;
    int rem = t & (NQ * NQ - 1);
    int i = rem >> 9;        // row: curr box
    int j = rem & (NQ - 1);  // col: filtered box
    float4 cb = ((const float4*)curr_boxes)[(b << 9) + i];
    float ax = cb.x - 0.5f * cb.z, ay = cb.y - 0.5f * cb.w;
    float az = cb.x + 0.5f * cb.z, aw = cb.y + 0.5f * cb.w;
    float4 fb = filt[(b << 9) + j];
    float bx = fb.x, by = fb.y, bz = fb.z, bw = fb.w;
    float area_a = (az - ax) * (aw - ay);
    float area_b = (bz - bx) * (bw - by);
    float ltx = fmaxf(ax, bx), lty = fmaxf(ay, by);
    float rbx = fminf(az, bz), rby = fminf(aw, bw);
    float w = fmaxf(rbx - ltx, 0.f), h = fmaxf(rby - lty, 0.f);
    float inter = w * h;
    float uni = area_a + area_b - inter;
    float iou = inter / (uni + 1e-7f);
    float lcx = fminf(ax, bx), lcy = fminf(ay, by);
    float rcx = fmaxf(az, bz), rcy = fmaxf(aw, bw);
    float wc = fmaxf(rcx - lcx, 0.f), hc = fmaxf(rcy - lcy, 0.f);
    float areac = wc * hc;
    float giou = iou - (areac - uni) / (areac + 1e-7f);
    float gl = 1.f - giou;
    u64 m = __ballot(gl < 0.2f);
    if ((threadIdx.x & 63) == 0)
        cost[(size_t)b * (NQ * 8) + ((size_t)(j >> 6) << 9) + i] = m;
}

// Exact integer replication of the reference JV Hungarian on a {0,1} cost
// matrix + fused CIoU epilogue.
// R11: the whole event walk now runs wave-synchronously on wave 0 — no
// __syncthreads round trips, no zcS/apS shared-memory handoffs. On entry
// to word g the 64 lanes cache their own row (8 u64) in registers; the
// ap word for the current Zc is ONE ballot over (R & Zc), recomputed in
// ~250 cyc per owner change (vs ~950 cyc for the R10 block round trip).
// Rows retire strictly in ascending order, so only the current word's ap
// is ever needed. LDS writes in the uniform walk are lane-0-guarded;
// reads are wave-broadcast. runGeneral (exact fallback) stays lane-0.
__global__ __launch_bounds__(256, 1) void hungarian_kernel(
        const u64* __restrict__ cost,
        const float* __restrict__ curr_boxes,
        const float4* __restrict__ filt,
        float* __restrict__ out) {
    int b = blockIdx.x;
    int tid = threadIdx.x;
    int lane = tid & 63;
    int wv = tid >> 6;
    __shared__ __align__(16) u64 costL[NQ * 8];   // 32 KB, word-major
    __shared__ int p[NQ + 1];
    __shared__ int wayL[NQ + 1];
    __shared__ int u[NQ + 1];
    __shared__ int vv[NQ + 1];
    __shared__ int minvA[NQ + 1];
    __shared__ unsigned char used[NQ + 1];

    {
        // global buffer is already word-major per batch -> straight copy
        const ulonglong2* src = (const ulonglong2*)(cost + (size_t)b * NQ * 8);
        ulonglong2* dst = (ulonglong2*)costL;
        for (int k = tid; k < NQ * 4; k += 256) dst[k] = src[k];
    }
    for (int k = tid; k <= NQ; k += 256) { p[k] = k; wayL[k] = 0; u[k] = 0; vv[k] = 0; }
    __syncthreads();

    if (wv == 0) {
        auto runGeneral = [&](int igen) {
            // exact general integer JV for rows igen..NQ (reference
            // semantics). lane-0 serial; never triggered on this data at
            // current timings but kept for exactness.
            for (int j = igen; j <= NQ; j++) p[j] = 0;
            for (int i2 = igen; i2 <= NQ; i2++) {
                p[0] = i2;
                for (int j = 0; j <= NQ; j++) { minvA[j] = 0x7fffffff; used[j] = 0; }
                int j0 = 0;
                while (true) {
                    used[j0] = 1;
                    int i0 = p[j0];
                    int ui0 = u[i0];
                    int delta = 0x7fffffff, j1 = 0;
                    for (int j = 1; j <= NQ; j++) {
                        if (!used[j]) {
                            int cbit = (int)((CW((j - 1) >> 6, i0 - 1) >> ((j - 1) & 63)) & 1ull);
                            int cur = cbit - ui0 - vv[j];
                            if (cur < minvA[j]) { minvA[j] = cur; wayL[j] = (i2 << 10) | j0; }
                            if (minvA[j] < delta) { delta = minvA[j]; j1 = j; }
                        }
                    }
                    for (int j = 0; j <= NQ; j++) {
                        if (used[j]) { u[p[j]] += delta; vv[j] -= delta; }
                        else minvA[j] -= delta;
                    }
                    j0 = j1;
                    if (p[j0] == 0) break;
                }
                while (j0) {
                    int wv2 = wayL[j0];
                    int jn = ((wv2 >> 10) == i2) ? (wv2 & 1023) : 0;
                    p[j0] = p[jn];
                    j0 = jn;
                }
            }
        };

        u64 Zc[8];
#pragma unroll
        for (int k = 0; k < 8; k++) Zc[k] = 0ull;
        int owner0 = 1;
        bool done = false;

        for (int g = 0; g < 8 && !done; g++) {
            // cache this word-group's rows in registers: lane owns row (g<<6)+lane
            u64 R[8];
            int r = (g << 6) + lane;
#pragma unroll
            for (int k = 0; k < 8; k++) R[k] = CW(k, r);
            u64 orR = 0ull;
#pragma unroll
            for (int k = 0; k < 8; k++) orR |= R[k];
            u64 nzw = __ballot(orR != 0ull);
            u64 c0w = __ballot((R[0] & 1ull) != 0ull);
            u64 dgw = __ballot(((getw8(R, g) >> lane) & 1ull) != 0ull);

            if (g == 0) {
                if ((nzw & c0w) & 1ull) {
                    // row 1 nz with cost[r1][c1]==1: exact general solve
                    if (lane == 0) runGeneral(1);
                    done = true;
                    break;
                }
                // owner of col 1 is row 1; its row (zero or not) is Zc
#pragma unroll
                for (int k = 0; k < 8; k++) Zc[k] = CW(k, 0);
            }
            u64 ao = 0ull;
#pragma unroll
            for (int k = 0; k < 8; k++) ao |= (R[k] & Zc[k]);
            u64 apw = __ballot(ao != 0ull);
            u64 bits = nzw & (c0w | dgw | apw);
            if (g == 0) bits &= ~1ull;

            while (bits) {
                int l = __builtin_ctzll(bits);
                u64 rem = (l == 63) ? 0ull : (~0ull << (l + 1));
                int i = (g << 6) + l + 1;   // 1-based row; cursor col = i-1
                bool c0 = (c0w >> l) & 1ull;
                bool apb = (apw >> l) & 1ull;
                if (!c0 && !apb) {
                    // diag event: relocation / swap. p[i]=owner0, p[1]=i.
                    if (lane == 0) { p[i] = owner0; p[1] = i; }
                    owner0 = i;
#pragma unroll
                    for (int k = 0; k < 8; k++) Zc[k] = CW(k, i - 1);
                } else {
                    // full bitset search (zero duals)
                    bool bail = false, hole = false;
                    u64 Z[8];
#pragma unroll
                    for (int k = 0; k < 8; k++) Z[k] = CW(k, i - 1);
                    u64 ones[8], vis[8], nzA[8], nzBf[8];
#pragma unroll
                    for (int k = 0; k < 8; k++) { ones[k] = Z[k]; vis[k] = 0ull; nzA[k] = 0ull; nzBf[k] = 0ull; }
                    int fA_c = 0, fA_p = 0, fB_c = 0, fB_p = 0;
                    int foldn = 0, assignTo = -1;
                    while (true) {
                        int c2 = -1;
#pragma unroll
                        for (int k = 7; k >= 0; k--) {
                            u64 s = ~ones[k] & ~vis[k];
                            if (s != 0ull) c2 = (k << 6) + __builtin_ctzll(s);
                        }
                        if (c2 < 0) { bail = true; break; }       // delta>0 needed
                        if (c2 >= i - 1) {                        // free region
                            if (c2 == i - 1) assignTo = c2;
                            else hole = true;                     // free above cursor
                            break;
                        }
                        int pc = p[c2 + 1];
                        u64 Zo[8];
#pragma unroll
                        for (int k = 0; k < 8; k++) Zo[k] = CW(k, pc - 1);
                        setbit8(vis, c2);
                        u64 nzv[8], ap2 = 0ull;
#pragma unroll
                        for (int k = 0; k < 8; k++) { nzv[k] = ones[k] & ~Zo[k]; ones[k] &= Zo[k]; ap2 |= ones[k]; }
                        if (foldn == 0) {
                            fA_c = c2; fA_p = pc;
#pragma unroll
                            for (int k = 0; k < 8; k++) nzA[k] = nzv[k];
                        } else if (foldn == 1) {
                            fB_c = c2; fB_p = pc;
#pragma unroll
                            for (int k = 0; k < 8; k++) nzBf[k] = nzv[k];
                        } else {
                            if (lane == 0) {
#pragma unroll
                                for (int k = 0; k < 8; k++) {
                                    u64 tt = nzv[k];
                                    while (tt) { int b2 = __builtin_ctzll(tt); tt &= tt - 1; wayL[(k << 6) + b2 + 1] = (i << 10) | (c2 + 1); }
                                }
                            }
                        }
                        foldn++;
                        if (ap2 == 0ull) { assignTo = i - 1; break; }   // shortcut -> cursor
                    }
                    if (bail || hole) {
                        if (lane == 0) runGeneral(i);
                        done = true;
                        break;
                    }
                    int cc = assignTo;
                    while (true) {
                        bool inA = getbit8(nzA, cc), inB = getbit8(nzBf, cc);
                        if (inB)      { if (lane == 0) p[cc + 1] = fB_p; cc = fB_c; }
                        else if (inA) { if (lane == 0) p[cc + 1] = fA_p; cc = fA_c; }
                        else if (foldn > 2) {
                            int wv2 = wayL[cc + 1];
                            if ((wv2 >> 10) == i) { int jn = wv2 & 1023; int pv = p[jn]; if (lane == 0) p[cc + 1] = pv; cc = jn - 1; }
                            else                  { if (lane == 0) p[cc + 1] = i; break; }
                        } else { if (lane == 0) p[cc + 1] = i; break; }
                    }
                    owner0 = p[1];
#pragma unroll
                    for (int k = 0; k < 8; k++) Zc[k] = CW(k, owner0 - 1);
                }
                // single-ballot ap refresh for the current word
                u64 ao2 = 0ull;
#pragma unroll
                for (int k = 0; k < 8; k++) ao2 |= (R[k] & Zc[k]);
                apw = __ballot(ao2 != 0ull);
                bits = nzw & (c0w | dgw | apw) & rem;
            }
        }
    }
    __syncthreads();

    // Fused CIoU epilogue: p is a permutation, so summing over columns j
    // (curr idx j-1, filtered idx p[j]-1) == summing over rows.
    {
#pragma clang fp contract(off)
        float sum = 0.f;
#pragma unroll
        for (int k = 0; k < 2; k++) {
            int j = 1 + tid + (k << 8);
            int r = p[j] - 1;     // filtered row
            int c = j - 1;        // curr box index
            float4 cb = ((const float4*)curr_boxes)[(b << 9) + c];
            float x1 = cb.x - 0.5f * cb.z, y1 = cb.y - 0.5f * cb.w;
            float x2 = cb.x + 0.5f * cb.z, y2 = cb.y + 0.5f * cb.w;
            float4 fb = filt[(b << 9) + r];
            float xg1 = fb.x, yg1 = fb.y, xg2 = fb.z, yg2 = fb.w;
            float iw = fmaxf(fminf(x2, xg2) - fmaxf(x1, xg1), 0.f);
            float ih = fmaxf(fminf(y2, yg2) - fmaxf(y1, yg1), 0.f);
            float inter = iw * ih;
            float uni = (x2 - x1) * (y2 - y1) + (xg2 - xg1) * (yg2 - yg1) - inter;
            float iou = inter / (uni + 1e-7f);
            float cw2 = fmaxf(x2, xg2) - fminf(x1, xg1);
            float ch2 = fmaxf(y2, yg2) - fminf(y1, yg1);
            float c2 = cw2 * cw2 + ch2 * ch2 + 1e-7f;
            float dx = ((x1 + x2) - xg1) - xg2;
            float dy = ((y1 + y2) - yg1) - yg2;
            float d2 = (dx * dx + dy * dy) / 4.f;
            const float CC = (float)(4.0 / (M_PI * M_PI));
            float at = atanf((xg2 - xg1) / (yg2 - yg1)) - atanf((x2 - x1) / (y2 - y1));
            float v = CC * (at * at);
            float alpha = v / (((1.f - iou) + v) + 1e-7f);
            sum += ((1.f - iou) + d2 / c2) + alpha * v;
        }
#pragma unroll
        for (int off = 32; off >= 1; off >>= 1) sum += __shfl_xor(sum, off, 64);
        if (lane == 0) atomicAdd(out, sum * (1.f / 4096.f));
    }
}

extern "C" void kernel_launch(void* const* d_in, const int* in_sizes, int n_in,
                              void* d_out, int out_size, void* d_ws, size_t ws_size,
                              hipStream_t stream) {
    const float* prev_boxes  = (const float*)d_in[0];
    // d_in[1] = prev_logits : dead code (Kalman innovation == 0 exactly)
    const float* curr_boxes  = (const float*)d_in[2];
    const float* image_sizes = (const float*)d_in[3];
    // d_in[4..6] (std weights, log_q_diag) : dead code

    float4* filt = (float4*)d_ws;                          // 64 KB
    u64* cost = (u64*)((char*)d_ws + 65536);               // 256 KB
    float* out = (float*)d_out;

    prep_kernel<<<(NB * NQ) / 256, 256, 0, stream>>>(
        prev_boxes, image_sizes, filt, out);
    cost_kernel<<<(NB * NQ * NQ) / 256, 256, 0, stream>>>(
        curr_boxes, filt, cost);
    hungarian_kernel<<<NB, 256, 0, stream>>>(
        cost, curr_boxes, filt, out);
}

// Round 3
// 77.701 us; speedup vs baseline: 1.0381x; 1.0003x over previous
//
#include <hip/hip_runtime.h>
#include <stdint.h>
#include <math.h>

#define NB 8
#define NQ 512

typedef unsigned long long u64;

// Word-major (transposed) cost tile: word k (columns 64k..64k+63) of row r.
#define CW(k, r) costL[((k) << 9) + (r)]

// ---- register-array helpers: constant-index-only access (no scratch spills) ----
static __device__ __forceinline__ u64 getw8(const u64 (&a)[8], int w) {
    u64 r = 0ull;
#pragma unroll
    for (int k = 0; k < 8; k++) if (k == w) r = a[k];
    return r;
}
static __device__ __forceinline__ void setbit8(u64 (&a)[8], int c) {
    int w = c >> 6; u64 m = 1ull << (c & 63);
#pragma unroll
    for (int k = 0; k < 8; k++) if (k == w) a[k] |= m;
}
static __device__ __forceinline__ bool getbit8(const u64 (&a)[8], int c) {
    return (getw8(a, c >> 6) >> (c & 63)) & 1ull;
}

// Filtered-box conversion (4 IEEE divides) once per (b,j).
// Ops bit-identical to the reference sequence (fp contract off).
__global__ void prep_kernel(const float* __restrict__ prev_boxes,
                            const float* __restrict__ image_sizes,
                            float4* __restrict__ filt,
                            float* __restrict__ out) {
#pragma clang fp contract(off)
    int t = blockIdx.x * blockDim.x + threadIdx.x;   // 0 .. NB*NQ-1
    if (t == 0) out[0] = 0.f;
    int b = t >> 9;
    float4 pb = ((const float4*)prev_boxes)[t];
    float H = image_sizes[2 * b + 0];
    float W = image_sizes[2 * b + 1];
    float fcx = (pb.x * W) / W, fcy = (pb.y * H) / H;
    float fw  = (pb.z * W) / W, fh  = (pb.w * H) / H;
    filt[t] = make_float4(fcx - 0.5f * fw, fcy - 0.5f * fh,
                          fcx + 0.5f * fw, fcy + 0.5f * fh);
}

// Fused cost: reads prepped filtered xyxy; writes the cost bitmatrix
// TRANSPOSED (word-major): cost[b*4096 + (j>>6)*512 + i].
// R12: 2048 blocks x 4-item grid-stride (G11: cap blocks, stride the rest)
// to cut dispatch ramp; per-wave j-contiguity (ballot layout) preserved
// since the stride is a multiple of 512.
__global__ void cost_kernel(const float* __restrict__ curr_boxes,
                            const float4* __restrict__ filt,
                            u64* __restrict__ cost) {
#pragma clang fp contract(off)
    int t0 = blockIdx.x * blockDim.x + threadIdx.x;  // 0 .. T/4-1
#pragma unroll
    for (int rep = 0; rep < 4; rep++) {
        int t = t0 + rep * (NB * NQ * NQ / 4);
        int b = t >> 18;
        int rem = t & (NQ * NQ - 1);
        int i = rem >> 9;        // row: curr box
        int j = rem & (NQ - 1);  // col: filtered box
        float4 cb = ((const float4*)curr_boxes)[(b << 9) + i];
        float ax = cb.x - 0.5f * cb.z, ay = cb.y - 0.5f * cb.w;
        float az = cb.x + 0.5f * cb.z, aw = cb.y + 0.5f * cb.w;
        float4 fb = filt[(b << 9) + j];
        float bx = fb.x, by = fb.y, bz = fb.z, bw = fb.w;
        float area_a = (az - ax) * (aw - ay);
        float area_b = (bz - bx) * (bw - by);
        float ltx = fmaxf(ax, bx), lty = fmaxf(ay, by);
        float rbx = fminf(az, bz), rby = fminf(aw, bw);
        float w = fmaxf(rbx - ltx, 0.f), h = fmaxf(rby - lty, 0.f);
        float inter = w * h;
        float uni = area_a + area_b - inter;
        float iou = inter / (uni + 1e-7f);
        float lcx = fminf(ax, bx), lcy = fminf(ay, by);
        float rcx = fmaxf(az, bz), rcy = fmaxf(aw, bw);
        float wc = fmaxf(rcx - lcx, 0.f), hc = fmaxf(rcy - lcy, 0.f);
        float areac = wc * hc;
        float giou = iou - (areac - uni) / (areac + 1e-7f);
        float gl = 1.f - giou;
        u64 m = __ballot(gl < 0.2f);
        if ((threadIdx.x & 63) == 0)
            cost[(size_t)b * (NQ * 8) + ((size_t)(j >> 6) << 9) + i] = m;
    }
}

// Exact integer replication of the reference JV Hungarian on a {0,1} cost
// matrix + fused CIoU epilogue.
// R11: whole event walk wave-synchronous on wave 0 (no block round trips).
// R12: while wave 0 walks (~3 us), waves 1-3 precompute ALL epilogue-
// invariant data into LDS: fbL/cbL box copies + the two atan terms per
// box (bit-identical op sequences). The epilogue is then pure-LDS + ~40
// VALU per item: no p-dependent global load, no atanf/divide on the
// critical path after the walk.
__global__ __launch_bounds__(256, 1) void hungarian_kernel(
        const u64* __restrict__ cost,
        const float* __restrict__ curr_boxes,
        const float4* __restrict__ filt,
        float* __restrict__ out) {
    int b = blockIdx.x;
    int tid = threadIdx.x;
    int lane = tid & 63;
    int wv = tid >> 6;
    __shared__ __align__(16) u64 costL[NQ * 8];   // 32 KB, word-major
    __shared__ int p[NQ + 1];
    __shared__ int wayL[NQ + 1];
    __shared__ int u[NQ + 1];
    __shared__ int vv[NQ + 1];
    __shared__ int minvA[NQ + 1];
    __shared__ unsigned char used[NQ + 1];
    __shared__ __align__(16) float4 fbL[NQ];      // 8 KB filtered xyxy
    __shared__ __align__(16) float4 cbL[NQ];      // 8 KB curr cxcywh
    __shared__ float atF[NQ];                     // atan terms (filtered)
    __shared__ float atC[NQ];                     // atan terms (curr)

    {
        // global buffer is already word-major per batch -> straight copy
        const ulonglong2* src = (const ulonglong2*)(cost + (size_t)b * NQ * 8);
        ulonglong2* dst = (ulonglong2*)costL;
#pragma unroll
        for (int it = 0; it < 8; it++) {
            int k = tid + (it << 8);
            dst[k] = src[k];
        }
    }
    for (int k = tid; k <= NQ; k += 256) { p[k] = k; wayL[k] = 0; u[k] = 0; vv[k] = 0; }
    __syncthreads();

    if (wv == 0) {
        auto runGeneral = [&](int igen) {
            // exact general integer JV for rows igen..NQ (reference
            // semantics). lane-0 serial; never fires on this data at
            // current timings but kept for exactness.
            for (int j = igen; j <= NQ; j++) p[j] = 0;
            for (int i2 = igen; i2 <= NQ; i2++) {
                p[0] = i2;
                for (int j = 0; j <= NQ; j++) { minvA[j] = 0x7fffffff; used[j] = 0; }
                int j0 = 0;
                while (true) {
                    used[j0] = 1;
                    int i0 = p[j0];
                    int ui0 = u[i0];
                    int delta = 0x7fffffff, j1 = 0;
                    for (int j = 1; j <= NQ; j++) {
                        if (!used[j]) {
                            int cbit = (int)((CW((j - 1) >> 6, i0 - 1) >> ((j - 1) & 63)) & 1ull);
                            int cur = cbit - ui0 - vv[j];
                            if (cur < minvA[j]) { minvA[j] = cur; wayL[j] = (i2 << 10) | j0; }
                            if (minvA[j] < delta) { delta = minvA[j]; j1 = j; }
                        }
                    }
                    for (int j = 0; j <= NQ; j++) {
                        if (used[j]) { u[p[j]] += delta; vv[j] -= delta; }
                        else minvA[j] -= delta;
                    }
                    j0 = j1;
                    if (p[j0] == 0) break;
                }
                while (j0) {
                    int wv2 = wayL[j0];
                    int jn = ((wv2 >> 10) == i2) ? (wv2 & 1023) : 0;
                    p[j0] = p[jn];
                    j0 = jn;
                }
            }
        };

        u64 Zc[8];
#pragma unroll
        for (int k = 0; k < 8; k++) Zc[k] = 0ull;
        int owner0 = 1;
        bool done = false;

        for (int g = 0; g < 8 && !done; g++) {
            // cache this word-group's rows in registers: lane owns row (g<<6)+lane
            u64 R[8];
            int r = (g << 6) + lane;
#pragma unroll
            for (int k = 0; k < 8; k++) R[k] = CW(k, r);
            u64 orR = 0ull;
#pragma unroll
            for (int k = 0; k < 8; k++) orR |= R[k];
            u64 nzw = __ballot(orR != 0ull);
            u64 c0w = __ballot((R[0] & 1ull) != 0ull);
            u64 dgw = __ballot(((getw8(R, g) >> lane) & 1ull) != 0ull);

            if (g == 0) {
                if ((nzw & c0w) & 1ull) {
                    // row 1 nz with cost[r1][c1]==1: exact general solve
                    if (lane == 0) runGeneral(1);
                    done = true;
                    break;
                }
                // owner of col 1 is row 1; its row (zero or not) is Zc
#pragma unroll
                for (int k = 0; k < 8; k++) Zc[k] = CW(k, 0);
            }
            u64 ao = 0ull;
#pragma unroll
            for (int k = 0; k < 8; k++) ao |= (R[k] & Zc[k]);
            u64 apw = __ballot(ao != 0ull);
            u64 bits = nzw & (c0w | dgw | apw);
            if (g == 0) bits &= ~1ull;

            while (bits) {
                int l = __builtin_ctzll(bits);
                u64 rem = (l == 63) ? 0ull : (~0ull << (l + 1));
                int i = (g << 6) + l + 1;   // 1-based row; cursor col = i-1
                bool c0 = (c0w >> l) & 1ull;
                bool apb = (apw >> l) & 1ull;
                if (!c0 && !apb) {
                    // diag event: relocation / swap. p[i]=owner0, p[1]=i.
                    if (lane == 0) { p[i] = owner0; p[1] = i; }
                    owner0 = i;
#pragma unroll
                    for (int k = 0; k < 8; k++) Zc[k] = CW(k, i - 1);
                } else {
                    // full bitset search (zero duals)
                    bool bail = false, hole = false;
                    u64 Z[8];
#pragma unroll
                    for (int k = 0; k < 8; k++) Z[k] = CW(k, i - 1);
                    u64 ones[8], vis[8], nzA[8], nzBf[8];
#pragma unroll
                    for (int k = 0; k < 8; k++) { ones[k] = Z[k]; vis[k] = 0ull; nzA[k] = 0ull; nzBf[k] = 0ull; }
                    int fA_c = 0, fA_p = 0, fB_c = 0, fB_p = 0;
                    int foldn = 0, assignTo = -1;
                    while (true) {
                        int c2 = -1;
#pragma unroll
                        for (int k = 7; k >= 0; k--) {
                            u64 s = ~ones[k] & ~vis[k];
                            if (s != 0ull) c2 = (k << 6) + __builtin_ctzll(s);
                        }
                        if (c2 < 0) { bail = true; break; }       // delta>0 needed
                        if (c2 >= i - 1) {                        // free region
                            if (c2 == i - 1) assignTo = c2;
                            else hole = true;                     // free above cursor
                            break;
                        }
                        int pc = p[c2 + 1];
                        u64 Zo[8];
#pragma unroll
                        for (int k = 0; k < 8; k++) Zo[k] = CW(k, pc - 1);
                        setbit8(vis, c2);
                        u64 nzv[8], ap2 = 0ull;
#pragma unroll
                        for (int k = 0; k < 8; k++) { nzv[k] = ones[k] & ~Zo[k]; ones[k] &= Zo[k]; ap2 |= ones[k]; }
                        if (foldn == 0) {
                            fA_c = c2; fA_p = pc;
#pragma unroll
                            for (int k = 0; k < 8; k++) nzA[k] = nzv[k];
                        } else if (foldn == 1) {
                            fB_c = c2; fB_p = pc;
#pragma unroll
                            for (int k = 0; k < 8; k++) nzBf[k] = nzv[k];
                        } else {
                            if (lane == 0) {
#pragma unroll
                                for (int k = 0; k < 8; k++) {
                                    u64 tt = nzv[k];
                                    while (tt) { int b2 = __builtin_ctzll(tt); tt &= tt - 1; wayL[(k << 6) + b2 + 1] = (i << 10) | (c2 + 1); }
                                }
                            }
                        }
                        foldn++;
                        if (ap2 == 0ull) { assignTo = i - 1; break; }   // shortcut -> cursor
                    }
                    if (bail || hole) {
                        if (lane == 0) runGeneral(i);
                        done = true;
                        break;
                    }
                    int cc = assignTo;
                    while (true) {
                        bool inA = getbit8(nzA, cc), inB = getbit8(nzBf, cc);
                        if (inB)      { if (lane == 0) p[cc + 1] = fB_p; cc = fB_c; }
                        else if (inA) { if (lane == 0) p[cc + 1] = fA_p; cc = fA_c; }
                        else if (foldn > 2) {
                            int wv2 = wayL[cc + 1];
                            if ((wv2 >> 10) == i) { int jn = wv2 & 1023; int pv = p[jn]; if (lane == 0) p[cc + 1] = pv; cc = jn - 1; }
                            else                  { if (lane == 0) p[cc + 1] = i; break; }
                        } else { if (lane == 0) p[cc + 1] = i; break; }
                    }
                    owner0 = p[1];
#pragma unroll
                    for (int k = 0; k < 8; k++) Zc[k] = CW(k, owner0 - 1);
                }
                // single-ballot ap refresh for the current word
                u64 ao2 = 0ull;
#pragma unroll
                for (int k = 0; k < 8; k++) ao2 |= (R[k] & Zc[k]);
                apw = __ballot(ao2 != 0ull);
                bits = nzw & (c0w | dgw | apw) & rem;
            }
        }
    } else {
        // waves 1-3: epilogue precompute, overlapped with wave 0's walk.
        // Bit-identical op sequences to the former inline epilogue code.
#pragma clang fp contract(off)
        int q = tid - 64;
        for (int r = q; r < NQ; r += 192) {
            float4 fb = filt[(b << 9) + r];
            fbL[r] = fb;
            float xg1 = fb.x, yg1 = fb.y, xg2 = fb.z, yg2 = fb.w;
            atF[r] = atanf((xg2 - xg1) / (yg2 - yg1));
            float4 cbv = ((const float4*)curr_boxes)[(b << 9) + r];
            cbL[r] = cbv;
            float x1 = cbv.x - 0.5f * cbv.z, y1 = cbv.y - 0.5f * cbv.w;
            float x2 = cbv.x + 0.5f * cbv.z, y2 = cbv.y + 0.5f * cbv.w;
            atC[r] = atanf((x2 - x1) / (y2 - y1));
        }
    }
    __syncthreads();

    // Fused CIoU epilogue: p is a permutation, so summing over columns j
    // (curr idx j-1, filtered idx p[j]-1) == summing over rows.
    // Pure-LDS inputs; atan terms precomputed (atF[r] - atC[c] is the
    // identical float subtract of the identical atanf results).
    {
#pragma clang fp contract(off)
        float sum = 0.f;
#pragma unroll
        for (int k = 0; k < 2; k++) {
            int j = 1 + tid + (k << 8);
            int r = p[j] - 1;     // filtered row
            int c = j - 1;        // curr box index
            float4 cb = cbL[c];
            float x1 = cb.x - 0.5f * cb.z, y1 = cb.y - 0.5f * cb.w;
            float x2 = cb.x + 0.5f * cb.z, y2 = cb.y + 0.5f * cb.w;
            float4 fb = fbL[r];
            float xg1 = fb.x, yg1 = fb.y, xg2 = fb.z, yg2 = fb.w;
            float iw = fmaxf(fminf(x2, xg2) - fmaxf(x1, xg1), 0.f);
            float ih = fmaxf(fminf(y2, yg2) - fmaxf(y1, yg1), 0.f);
            float inter = iw * ih;
            float uni = (x2 - x1) * (y2 - y1) + (xg2 - xg1) * (yg2 - yg1) - inter;
            float iou = inter / (uni + 1e-7f);
            float cw2 = fmaxf(x2, xg2) - fminf(x1, xg1);
            float ch2 = fmaxf(y2, yg2) - fminf(y1, yg1);
            float c2 = cw2 * cw2 + ch2 * ch2 + 1e-7f;
            float dx = ((x1 + x2) - xg1) - xg2;
            float dy = ((y1 + y2) - yg1) - yg2;
            float d2 = (dx * dx + dy * dy) / 4.f;
            const float CC = (float)(4.0 / (M_PI * M_PI));
            float at = atF[r] - atC[c];
            float v = CC * (at * at);
            float alpha = v / (((1.f - iou) + v) + 1e-7f);
            sum += ((1.f - iou) + d2 / c2) + alpha * v;
        }
#pragma unroll
        for (int off = 32; off >= 1; off >>= 1) sum += __shfl_xor(sum, off, 64);
        if (lane == 0) atomicAdd(out, sum * (1.f / 4096.f));
    }
}

extern "C" void kernel_launch(void* const* d_in, const int* in_sizes, int n_in,
                              void* d_out, int out_size, void* d_ws, size_t ws_size,
                              hipStream_t stream) {
    const float* prev_boxes  = (const float*)d_in[0];
    // d_in[1] = prev_logits : dead code (Kalman innovation == 0 exactly)
    const float* curr_boxes  = (const float*)d_in[2];
    const float* image_sizes = (const float*)d_in[3];
    // d_in[4..6] (std weights, log_q_diag) : dead code

    float4* filt = (float4*)d_ws;                          // 64 KB
    u64* cost = (u64*)((char*)d_ws + 65536);               // 256 KB
    float* out = (float*)d_out;

    prep_kernel<<<(NB * NQ) / 256, 256, 0, stream>>>(
        prev_boxes, image_sizes, filt, out);
    cost_kernel<<<(NB * NQ * NQ / 4) / 256, 256, 0, stream>>>(
        curr_boxes, filt, cost);
    hungarian_kernel<<<NB, 256, 0, stream>>>(
        cost, curr_boxes, filt, out);
}